// Round 1
// baseline (381.935 us; speedup 1.0000x reference)
//
#include <hip/hip_runtime.h>

constexpr float LN_EPS = 1e-5f;
constexpr float NEG_INF_V = -1e30f;

// reduce across the 16-lane tx group (lanes differing in bits 0..3)
__device__ __forceinline__ float rsum16(float v) {
    v += __shfl_xor(v, 1, 64);
    v += __shfl_xor(v, 2, 64);
    v += __shfl_xor(v, 4, 64);
    v += __shfl_xor(v, 8, 64);
    return v;
}
__device__ __forceinline__ float rmax16(float v) {
    v = fmaxf(v, __shfl_xor(v, 1, 64));
    v = fmaxf(v, __shfl_xor(v, 2, 64));
    v = fmaxf(v, __shfl_xor(v, 4, 64));
    v = fmaxf(v, __shfl_xor(v, 8, 64));
    return v;
}

__global__ __launch_bounds__(256, 2)
void attn_kernel(const float* __restrict__ fi,
                 const float* __restrict__ corr,
                 const float* __restrict__ ln_g,
                 const float* __restrict__ ln_b,
                 const float* __restrict__ lw,
                 const float* __restrict__ lb,
                 float* __restrict__ out)
{
    __shared__ float sFr[64][64];  // fi row-major            (M3 B, final)
    __shared__ float sFt[64][64];  // fi transposed sFt[d][i] (M1 A, M2 B)
    __shared__ float sCA[64][64];  // C row-major (M1 B), then alpha^T (M3 A)
    __shared__ float sPt[64][64];  // fiC transposed sPt[e][i] (M2 A)

    const int tid = threadIdx.x;
    const int tx  = tid & 15;   // output-column group
    const int ty  = tid >> 4;   // output-row group
    const int i0  = ty << 2;
    const int j0  = tx << 2;

    // ---- Stage 0: load fi (row + transposed) and C ----
    {
        const float4* f4 = (const float4*)(fi + (size_t)blockIdx.x * 4096);
        const float4* c4 = (const float4*)corr;
        #pragma unroll
        for (int it = 0; it < 4; ++it) {
            int idx = tid + it * 256;
            int r = idx >> 4;
            int c = (idx & 15) << 2;
            float4 v = f4[idx];
            *(float4*)&sFr[r][c] = v;
            sFt[c + 0][r] = v.x;
            sFt[c + 1][r] = v.y;
            sFt[c + 2][r] = v.z;
            sFt[c + 3][r] = v.w;
            *(float4*)&sCA[r][c] = c4[idx];
        }
    }
    __syncthreads();

    float acc[4][4];

    // ---- M1: fiC = fi @ C, write transposed into sPt ----
    #pragma unroll
    for (int r = 0; r < 4; ++r)
        #pragma unroll
        for (int c = 0; c < 4; ++c) acc[r][c] = 0.f;

    #pragma unroll 4
    for (int d = 0; d < 64; ++d) {
        float4 a = *(const float4*)&sFt[d][i0];   // fi[i0..i0+3][d]
        float4 b = *(const float4*)&sCA[d][j0];   // C[d][j0..j0+3]
        float av[4] = {a.x, a.y, a.z, a.w};
        float bv[4] = {b.x, b.y, b.z, b.w};
        #pragma unroll
        for (int r = 0; r < 4; ++r)
            #pragma unroll
            for (int c = 0; c < 4; ++c)
                acc[r][c] = fmaf(av[r], bv[c], acc[r][c]);
    }
    #pragma unroll
    for (int c = 0; c < 4; ++c)
        *(float4*)&sPt[j0 + c][i0] =
            make_float4(acc[0][c], acc[1][c], acc[2][c], acc[3][c]);
    __syncthreads();

    // ---- M2: beta = fiC @ fi^T ----
    #pragma unroll
    for (int r = 0; r < 4; ++r)
        #pragma unroll
        for (int c = 0; c < 4; ++c) acc[r][c] = 0.f;

    #pragma unroll 4
    for (int e = 0; e < 64; ++e) {
        float4 a = *(const float4*)&sPt[e][i0];   // fiC[i0..i0+3][e]
        float4 b = *(const float4*)&sFt[e][j0];   // fi[j0..j0+3][e]
        float av[4] = {a.x, a.y, a.z, a.w};
        float bv[4] = {b.x, b.y, b.z, b.w};
        #pragma unroll
        for (int r = 0; r < 4; ++r)
            #pragma unroll
            for (int c = 0; c < 4; ++c)
                acc[r][c] = fmaf(av[r], bv[c], acc[r][c]);
    }

    // ---- mask diag + row softmax (rows spread over 16 tx-lanes) ----
    float alpha[4][4];
    #pragma unroll
    for (int r = 0; r < 4; ++r) {
        const int irow = i0 + r;
        #pragma unroll
        for (int c = 0; c < 4; ++c)
            if (irow == j0 + c) acc[r][c] = NEG_INF_V;
        float m = fmaxf(fmaxf(acc[r][0], acc[r][1]),
                        fmaxf(acc[r][2], acc[r][3]));
        m = rmax16(m);
        float s = 0.f;
        #pragma unroll
        for (int c = 0; c < 4; ++c) {
            alpha[r][c] = __expf(acc[r][c] - m);
            s += alpha[r][c];
        }
        s = rsum16(s);
        float inv = 1.0f / s;
        #pragma unroll
        for (int c = 0; c < 4; ++c) alpha[r][c] *= inv;
    }
    // alpha^T overwrites C (dead after M1; post-M1 barrier already passed)
    #pragma unroll
    for (int c = 0; c < 4; ++c)
        *(float4*)&sCA[j0 + c][i0] =
            make_float4(alpha[0][c], alpha[1][c], alpha[2][c], alpha[3][c]);
    __syncthreads();

    // ---- M3: vi = alpha @ fi ----
    #pragma unroll
    for (int r = 0; r < 4; ++r)
        #pragma unroll
        for (int c = 0; c < 4; ++c) acc[r][c] = 0.f;

    #pragma unroll 4
    for (int j = 0; j < 64; ++j) {
        float4 a = *(const float4*)&sCA[j][i0];   // alpha[i0..i0+3][j]
        float4 b = *(const float4*)&sFr[j][j0];   // fi[j][j0..j0+3]
        float av[4] = {a.x, a.y, a.z, a.w};
        float bv[4] = {b.x, b.y, b.z, b.w};
        #pragma unroll
        for (int r = 0; r < 4; ++r)
            #pragma unroll
            for (int c = 0; c < 4; ++c)
                acc[r][c] = fmaf(av[r], bv[c], acc[r][c]);
    }

    // ---- LN + ReLU + final dot + sigmoid ----
    float4 g4 = *(const float4*)&ln_g[j0];
    float4 b4 = *(const float4*)&ln_b[j0];
    float4 w0 = *(const float4*)&lw[j0];
    float4 w1 = *(const float4*)&lw[64 + j0];
    const float bias = lb[0];
    const float gv[4] = {g4.x, g4.y, g4.z, g4.w};
    const float bv2[4] = {b4.x, b4.y, b4.z, b4.w};
    const float w0v[4] = {w0.x, w0.y, w0.z, w0.w};
    const float w1v[4] = {w1.x, w1.y, w1.z, w1.w};

    float res[4];
    #pragma unroll
    for (int r = 0; r < 4; ++r) {
        float s = acc[r][0] + acc[r][1] + acc[r][2] + acc[r][3];
        s = rsum16(s);
        const float mu = s * (1.0f / 64.0f);
        float vsum = 0.f;
        #pragma unroll
        for (int c = 0; c < 4; ++c) {
            float d = acc[r][c] - mu;
            vsum += d * d;
        }
        vsum = rsum16(vsum) * (1.0f / 64.0f);
        const float rstd = rsqrtf(vsum + LN_EPS);

        float4 fr = *(const float4*)&sFr[i0 + r][j0];
        const float frv[4] = {fr.x, fr.y, fr.z, fr.w};
        float dot = 0.f;
        #pragma unroll
        for (int c = 0; c < 4; ++c) {
            float lnv = (acc[r][c] - mu) * rstd * gv[c] + bv2[c];
            lnv = fmaxf(lnv, 0.f);
            dot += lnv * w1v[c] + frv[c] * w0v[c];
        }
        dot = rsum16(dot);
        res[r] = 1.0f / (1.0f + __expf(-(dot + bias)));
    }
    if (tx == 0) {
        *(float4*)&out[(size_t)blockIdx.x * 64 + i0] =
            make_float4(res[0], res[1], res[2], res[3]);
    }
}

extern "C" void kernel_launch(void* const* d_in, const int* in_sizes, int n_in,
                              void* d_out, int out_size, void* d_ws, size_t ws_size,
                              hipStream_t stream) {
    const float* fi   = (const float*)d_in[0];
    const float* corr = (const float*)d_in[1];
    const float* g    = (const float*)d_in[2];
    const float* b    = (const float*)d_in[3];
    const float* lw   = (const float*)d_in[4];
    const float* lb   = (const float*)d_in[5];
    float* out        = (float*)d_out;
    const int B = in_sizes[0] / 4096;   // 8192 batches of 64x64
    hipLaunchKernelGGL(attn_kernel, dim3(B), dim3(256), 0, stream,
                       fi, corr, g, b, lw, lb, out);
}

// Round 2
// 293.012 us; speedup vs baseline: 1.3035x; 1.3035x over previous
//
#include <hip/hip_runtime.h>

typedef __attribute__((ext_vector_type(8))) short short8;
typedef __attribute__((ext_vector_type(4))) float floatx4;

constexpr float LN_EPS = 1e-5f;
constexpr float NEG_INF_V = -1e30f;

__device__ __forceinline__ unsigned short bf16hi(float x) {
    unsigned int u = __builtin_bit_cast(unsigned int, x);
    u += 0x7FFFu + ((u >> 16) & 1u);
    return (unsigned short)(u >> 16);
}
__device__ __forceinline__ float bf16f(unsigned short h) {
    unsigned int u = ((unsigned int)h) << 16;
    return __builtin_bit_cast(float, u);
}
__device__ __forceinline__ void bf16split(float x, unsigned short& h, unsigned short& l) {
    h = bf16hi(x);
    l = bf16hi(x - bf16f(h));
}

// XOR-swizzled 64x64 bf16 LDS layout: rows of 128B, 8 groups of 8 elems (16B);
// group for column-range [8g,8g+8) of row r sits at position g ^ ((r ^ r>>3)&7).
// Makes fragment b128 reads, staging b64 writes, and the transpose sliver
// pattern all (near-)conflict-free.
__device__ __forceinline__ int swzr(int r) { return (r ^ (r >> 3)) & 7; }
__device__ __forceinline__ int eoff(int r, int c) {   // element index
    return r * 64 + ((((c >> 3) ^ swzr(r)) & 7) << 3) + (c & 7);
}
__device__ __forceinline__ int goff(int r, int g) {   // 8-elem group index
    return r * 64 + (((g ^ swzr(r)) & 7) << 3);
}

__device__ __forceinline__ float rsum16(float v) {
    v += __shfl_xor(v, 1, 64);
    v += __shfl_xor(v, 2, 64);
    v += __shfl_xor(v, 4, 64);
    v += __shfl_xor(v, 8, 64);
    return v;
}
__device__ __forceinline__ float rmax16(float v) {
    v = fmaxf(v, __shfl_xor(v, 1, 64));
    v = fmaxf(v, __shfl_xor(v, 2, 64));
    v = fmaxf(v, __shfl_xor(v, 4, 64));
    v = fmaxf(v, __shfl_xor(v, 8, 64));
    return v;
}

// one-off: C (64x64 fp32, row-major) -> C^T as bf16 hi/lo arrays in d_ws
__global__ void prep_ct(const float* __restrict__ corr,
                        unsigned short* __restrict__ ct) {
    int t = threadIdx.x;
    #pragma unroll
    for (int it = 0; it < 16; ++it) {
        int idx = t + it * 256;
        int r = idx >> 6, c = idx & 63;
        float v = corr[idx];
        unsigned short h, l;
        bf16split(v, h, l);
        ct[c * 64 + r] = h;           // Ct_h row-major (= C col-major)
        ct[4096 + c * 64 + r] = l;    // Ct_l
    }
}

__global__ __launch_bounds__(256, 3)
void attn_mfma(const float* __restrict__ fi,
               const unsigned short* __restrict__ Ct,
               const float* __restrict__ ln_g,
               const float* __restrict__ ln_b,
               const float* __restrict__ lw,
               const float* __restrict__ lb,
               float* __restrict__ out)
{
    __shared__ __align__(16) unsigned short sFiH[4096], sFiL[4096]; // fi rows (later: alpha)
    __shared__ __align__(16) unsigned short sFtH[4096], sFtL[4096]; // fi^T rows
    __shared__ __align__(16) unsigned short sPH[4096],  sPL[4096];  // fiC rows
    __shared__ float dot0[64];   // per-row fi . w0 (fp32)

    const int tid  = threadIdx.x;
    const int lane = tid & 63;
    const int w    = tid >> 6;      // wave id 0..3 = row-stripe
    const int n    = lane & 15;
    const int quad = lane >> 4;
    const size_t blk = blockIdx.x;

    // ---- stage fi: fp32 -> bf16 hi/lo rows, plus dot0 = fi . w0 ----
    {
        const float4* f4 = (const float4*)(fi + blk * 4096);
        #pragma unroll
        for (int it = 0; it < 4; ++it) {
            int idx = tid + it * 256;
            int r = idx >> 4, c4 = (idx & 15) << 2;
            float4 v = f4[idx];
            unsigned short h0, l0, h1, l1, h2, l2, h3, l3;
            bf16split(v.x, h0, l0); bf16split(v.y, h1, l1);
            bf16split(v.z, h2, l2); bf16split(v.w, h3, l3);
            ushort4 vh = {h0, h1, h2, h3};
            ushort4 vl = {l0, l1, l2, l3};
            *(ushort4*)&sFiH[eoff(r, c4)] = vh;
            *(ushort4*)&sFiL[eoff(r, c4)] = vl;
            float4 w0v = *(const float4*)&lw[c4];
            float p = v.x * w0v.x + v.y * w0v.y + v.z * w0v.z + v.w * w0v.w;
            p = rsum16(p);
            if ((tid & 15) == 0) dot0[r] = p;
        }
    }
    __syncthreads();   // b1: sFi ready

    const int arow = 16 * w + n;   // A-fragment row for this lane

    // ---- M1: fiC = fi @ C  (A = fi from LDS, B = C via C^T from global) ----
    short8 Ah[2], Al[2];
    #pragma unroll
    for (int kk = 0; kk < 2; ++kk) {
        Ah[kk] = *(const short8*)&sFiH[goff(arow, kk * 4 + quad)];
        Al[kk] = *(const short8*)&sFiL[goff(arow, kk * 4 + quad)];
    }
    floatx4 acc1[4];
    #pragma unroll
    for (int t = 0; t < 4; ++t) {
        floatx4 a = {0.f, 0.f, 0.f, 0.f};
        const int brow = 16 * t + n;
        #pragma unroll
        for (int kk = 0; kk < 2; ++kk) {
            short8 bh = *(const short8*)&Ct[brow * 64 + kk * 32 + quad * 8];
            short8 bl = *(const short8*)&Ct[4096 + brow * 64 + kk * 32 + quad * 8];
            a = __builtin_amdgcn_mfma_f32_16x16x32_bf16(Ah[kk], bh, a, 0, 0, 0);
            a = __builtin_amdgcn_mfma_f32_16x16x32_bf16(Al[kk], bh, a, 0, 0, 0);
            a = __builtin_amdgcn_mfma_f32_16x16x32_bf16(Ah[kk], bl, a, 0, 0, 0);
        }
        acc1[t] = a;
    }
    // write fiC (C-layout: row = 16w + quad*4 + reg, col = 16t + n) to sP
    #pragma unroll
    for (int t = 0; t < 4; ++t)
        #pragma unroll
        for (int reg = 0; reg < 4; ++reg) {
            int row = 16 * w + quad * 4 + reg;
            int col = 16 * t + n;
            unsigned short h, l;
            bf16split(acc1[t][reg], h, l);
            sPH[eoff(row, col)] = h;
            sPL[eoff(row, col)] = l;
        }
    // ---- build fi^T: each lane moves two 8-row column slivers ----
    {
        const int s  = lane & 7;
        const int cb = w * 8 + (lane >> 3);
        #pragma unroll
        for (int half = 0; half < 2; ++half) {
            int c = cb + 32 * half;
            short8 vh, vl;
            #pragma unroll
            for (int m = 0; m < 8; ++m) {
                vh[m] = (short)sFiH[eoff(8 * s + m, c)];
                vl[m] = (short)sFiL[eoff(8 * s + m, c)];
            }
            *(short8*)&sFtH[goff(c, s)] = vh;
            *(short8*)&sFtL[goff(c, s)] = vl;
        }
    }
    __syncthreads();   // b2: sP + sFt ready

    // ---- M2: beta = fiC @ fi^T  (A = fiC rows, B^T = fi rows) ----
    #pragma unroll
    for (int kk = 0; kk < 2; ++kk) {
        Ah[kk] = *(const short8*)&sPH[goff(arow, kk * 4 + quad)];
        Al[kk] = *(const short8*)&sPL[goff(arow, kk * 4 + quad)];
    }
    floatx4 acc2[4];
    #pragma unroll
    for (int t = 0; t < 4; ++t) {
        floatx4 a = {0.f, 0.f, 0.f, 0.f};
        const int brow = 16 * t + n;
        #pragma unroll
        for (int kk = 0; kk < 2; ++kk) {
            short8 bh = *(const short8*)&sFiH[goff(brow, kk * 4 + quad)];
            short8 bl = *(const short8*)&sFiL[goff(brow, kk * 4 + quad)];
            a = __builtin_amdgcn_mfma_f32_16x16x32_bf16(Ah[kk], bh, a, 0, 0, 0);
            a = __builtin_amdgcn_mfma_f32_16x16x32_bf16(Al[kk], bh, a, 0, 0, 0);
            a = __builtin_amdgcn_mfma_f32_16x16x32_bf16(Ah[kk], bl, a, 0, 0, 0);
        }
        acc2[t] = a;
    }
    // ---- masked row softmax, fully in registers (rows live in-wave) ----
    float alv[4][4];   // [reg][t]
    #pragma unroll
    for (int reg = 0; reg < 4; ++reg) {
        const int row = 16 * w + quad * 4 + reg;
        float x[4];
        #pragma unroll
        for (int t = 0; t < 4; ++t) {
            x[t] = acc2[t][reg];
            if (row == 16 * t + n) x[t] = NEG_INF_V;
        }
        float m = fmaxf(fmaxf(x[0], x[1]), fmaxf(x[2], x[3]));
        m = rmax16(m);
        float s = 0.f;
        #pragma unroll
        for (int t = 0; t < 4; ++t) { x[t] = __expf(x[t] - m); s += x[t]; }
        s = rsum16(s);
        float inv = 1.0f / s;
        #pragma unroll
        for (int t = 0; t < 4; ++t) alv[reg][t] = x[t] * inv;
    }
    __syncthreads();   // b3: all waves done reading sFi (M2) — safe to overwrite
    #pragma unroll
    for (int reg = 0; reg < 4; ++reg)
        #pragma unroll
        for (int t = 0; t < 4; ++t) {
            int row = 16 * w + quad * 4 + reg;
            int col = 16 * t + n;
            unsigned short h, l;
            bf16split(alv[reg][t], h, l);
            sFiH[eoff(row, col)] = h;   // sFi reused as alpha
            sFiL[eoff(row, col)] = l;
        }
    __syncthreads();   // b4: alpha ready

    // ---- M3: vi = alpha @ fi  (A = alpha rows, B^T = fi^T rows) ----
    #pragma unroll
    for (int kk = 0; kk < 2; ++kk) {
        Ah[kk] = *(const short8*)&sFiH[goff(arow, kk * 4 + quad)];
        Al[kk] = *(const short8*)&sFiL[goff(arow, kk * 4 + quad)];
    }
    floatx4 acc3[4];
    #pragma unroll
    for (int t = 0; t < 4; ++t) {
        floatx4 a = {0.f, 0.f, 0.f, 0.f};
        const int brow = 16 * t + n;
        #pragma unroll
        for (int kk = 0; kk < 2; ++kk) {
            short8 bh = *(const short8*)&sFtH[goff(brow, kk * 4 + quad)];
            short8 bl = *(const short8*)&sFtL[goff(brow, kk * 4 + quad)];
            a = __builtin_amdgcn_mfma_f32_16x16x32_bf16(Ah[kk], bh, a, 0, 0, 0);
            a = __builtin_amdgcn_mfma_f32_16x16x32_bf16(Al[kk], bh, a, 0, 0, 0);
            a = __builtin_amdgcn_mfma_f32_16x16x32_bf16(Ah[kk], bl, a, 0, 0, 0);
        }
        acc3[t] = a;
    }

    // ---- LN + ReLU + final dot + sigmoid ----
    float gv[4], bv[4], w1v[4];
    #pragma unroll
    for (int t = 0; t < 4; ++t) {
        gv[t]  = ln_g[16 * t + n];
        bv[t]  = ln_b[16 * t + n];
        w1v[t] = lw[64 + 16 * t + n];
    }
    const float bias = lb[0];
    float res[4];
    #pragma unroll
    for (int reg = 0; reg < 4; ++reg) {
        const int row = 16 * w + quad * 4 + reg;
        float s = acc3[0][reg] + acc3[1][reg] + acc3[2][reg] + acc3[3][reg];
        s = rsum16(s);
        const float mu = s * (1.0f / 64.0f);
        float vs = 0.f;
        #pragma unroll
        for (int t = 0; t < 4; ++t) {
            float d = acc3[t][reg] - mu;
            vs += d * d;
        }
        vs = rsum16(vs) * (1.0f / 64.0f);
        const float rstd = rsqrtf(vs + LN_EPS);
        float dotp = 0.f;
        #pragma unroll
        for (int t = 0; t < 4; ++t) {
            float lnv = (acc3[t][reg] - mu) * rstd * gv[t] + bv[t];
            lnv = fmaxf(lnv, 0.f);
            dotp += lnv * w1v[t];
        }
        dotp = rsum16(dotp);
        res[reg] = 1.0f / (1.0f + __expf(-(dotp + dot0[row] + bias)));
    }
    if (n == 0) {
        float4 o = {res[0], res[1], res[2], res[3]};
        *(float4*)&out[blk * 64 + 16 * w + quad * 4] = o;
    }
}

extern "C" void kernel_launch(void* const* d_in, const int* in_sizes, int n_in,
                              void* d_out, int out_size, void* d_ws, size_t ws_size,
                              hipStream_t stream) {
    const float* fi   = (const float*)d_in[0];
    const float* corr = (const float*)d_in[1];
    const float* g    = (const float*)d_in[2];
    const float* b    = (const float*)d_in[3];
    const float* lw   = (const float*)d_in[4];
    const float* lb   = (const float*)d_in[5];
    float* out        = (float*)d_out;
    unsigned short* ct = (unsigned short*)d_ws;   // 16 KB: Ct_h | Ct_l

    const int B = in_sizes[0] / 4096;
    hipLaunchKernelGGL(prep_ct, dim3(1), dim3(256), 0, stream, corr, ct);
    hipLaunchKernelGGL(attn_mfma, dim3(B), dim3(256), 0, stream,
                       fi, ct, g, b, lw, lb, out);
}

// Round 3
// 250.396 us; speedup vs baseline: 1.5253x; 1.1702x over previous
//
#include <hip/hip_runtime.h>

typedef __attribute__((ext_vector_type(8))) short short8;
typedef __attribute__((ext_vector_type(4))) float floatx4;

constexpr float LN_EPS = 1e-5f;
constexpr float NEG_INF_V = -1e30f;

__device__ __forceinline__ unsigned short bf16hi(float x) {
    unsigned int u = __builtin_bit_cast(unsigned int, x);
    u += 0x7FFFu + ((u >> 16) & 1u);
    return (unsigned short)(u >> 16);
}
__device__ __forceinline__ float bf16f(unsigned short h) {
    unsigned int u = ((unsigned int)h) << 16;
    return __builtin_bit_cast(float, u);
}
__device__ __forceinline__ void bf16split(float x, unsigned short& h, unsigned short& l) {
    h = bf16hi(x);
    l = bf16hi(x - bf16f(h));
}

// XOR-swizzled 64x64 bf16 LDS layout (16B groups permuted within each 128B row)
__device__ __forceinline__ int swzr(int r) { return (r ^ (r >> 3)) & 7; }
__device__ __forceinline__ int eoff(int r, int c) {
    return r * 64 + ((((c >> 3) ^ swzr(r)) & 7) << 3) + (c & 7);
}
__device__ __forceinline__ int goff(int r, int g) {
    return r * 64 + (((g ^ swzr(r)) & 7) << 3);
}

__device__ __forceinline__ float rsum16(float v) {
    v += __shfl_xor(v, 1, 64);
    v += __shfl_xor(v, 2, 64);
    v += __shfl_xor(v, 4, 64);
    v += __shfl_xor(v, 8, 64);
    return v;
}
__device__ __forceinline__ float rmax16(float v) {
    v = fmaxf(v, __shfl_xor(v, 1, 64));
    v = fmaxf(v, __shfl_xor(v, 2, 64));
    v = fmaxf(v, __shfl_xor(v, 4, 64));
    v = fmaxf(v, __shfl_xor(v, 8, 64));
    return v;
}

// C (64x64 fp32) -> C^T bf16 hi/lo in d_ws. 16 blocks: fully parallel, ~1 us.
__global__ void prep_ct(const float* __restrict__ corr,
                        unsigned short* __restrict__ ct) {
    int idx = blockIdx.x * 256 + threadIdx.x;
    int r = idx >> 6, c = idx & 63;
    float v = corr[idx];
    unsigned short h, l;
    bf16split(v, h, l);
    ct[c * 64 + r] = h;
    ct[4096 + c * 64 + r] = l;
}

__global__ __launch_bounds__(256, 4)
void attn_mfma(const float* __restrict__ fi,
               const unsigned short* __restrict__ Ct,
               const float* __restrict__ ln_g,
               const float* __restrict__ ln_b,
               const float* __restrict__ lw,
               const float* __restrict__ lb,
               float* __restrict__ out)
{
    // 5 x 8 KB = 40960 B -> 4 blocks/CU
    __shared__ __align__(16) unsigned short sFiH[4096], sFiL[4096]; // fi rows h/l
    __shared__ __align__(16) unsigned short sFtH[4096];             // fi^T rows, hi
    __shared__ __align__(16) unsigned short sPH[4096], sPL[4096];   // fiC h/l, then alpha->sPH

    const int tid  = threadIdx.x;
    const int lane = tid & 63;
    const int w    = tid >> 6;
    const int n    = lane & 15;
    const int quad = lane >> 4;
    const size_t blk = blockIdx.x;

    // ---- staging: thread owns 16 elems of row r; builds sFi h/l, sFt hi, dot0 ----
    const int r = tid >> 2;
    const int a = tid & 3;
    float d0 = 0.f;
    {
        const float* fb = fi + blk * 4096 + (size_t)r * 64;
        #pragma unroll
        for (int i = 0; i < 4; ++i) {
            const int c = a * 4 + 16 * i;
            float4 v   = *(const float4*)(fb + c);
            float4 w0v = *(const float4*)&lw[c];
            d0 += v.x * w0v.x + v.y * w0v.y + v.z * w0v.z + v.w * w0v.w;
            unsigned short h0, l0, h1, l1, h2, l2, h3, l3;
            bf16split(v.x, h0, l0); bf16split(v.y, h1, l1);
            bf16split(v.z, h2, l2); bf16split(v.w, h3, l3);
            ushort4 vh = {h0, h1, h2, h3};
            ushort4 vl = {l0, l1, l2, l3};
            *(ushort4*)&sFiH[eoff(r, c)] = vh;
            *(ushort4*)&sFiL[eoff(r, c)] = vl;
            sFtH[eoff(c + 0, r)] = h0;
            sFtH[eoff(c + 1, r)] = h1;
            sFtH[eoff(c + 2, r)] = h2;
            sFtH[eoff(c + 3, r)] = h3;
        }
        d0 += __shfl_xor(d0, 1, 64);
        d0 += __shfl_xor(d0, 2, 64);   // all 4 threads of row r hold fi[r].w0
    }

    const int arow = 16 * w + n;

    // ---- M1: fiC = fi @ C (A: own-stripe sFi rows; B: C^T from global; NO barrier) ----
    short8 Ah[2], Al[2];
    #pragma unroll
    for (int kk = 0; kk < 2; ++kk) {
        Ah[kk] = *(const short8*)&sFiH[goff(arow, kk * 4 + quad)];
        Al[kk] = *(const short8*)&sFiL[goff(arow, kk * 4 + quad)];
    }
    floatx4 acc1[4];
    #pragma unroll
    for (int t = 0; t < 4; ++t) {
        floatx4 acc = {0.f, 0.f, 0.f, 0.f};
        const int brow = 16 * t + n;
        #pragma unroll
        for (int kk = 0; kk < 2; ++kk) {
            short8 bh = *(const short8*)&Ct[brow * 64 + kk * 32 + quad * 8];
            short8 bl = *(const short8*)&Ct[4096 + brow * 64 + kk * 32 + quad * 8];
            acc = __builtin_amdgcn_mfma_f32_16x16x32_bf16(Ah[kk], bh, acc, 0, 0, 0);
            acc = __builtin_amdgcn_mfma_f32_16x16x32_bf16(Al[kk], bh, acc, 0, 0, 0);
            acc = __builtin_amdgcn_mfma_f32_16x16x32_bf16(Ah[kk], bl, acc, 0, 0, 0);
        }
        acc1[t] = acc;
    }
    // fiC -> sP (wave-private rows [16w,16w+16))
    #pragma unroll
    for (int t = 0; t < 4; ++t)
        #pragma unroll
        for (int reg = 0; reg < 4; ++reg) {
            int row = 16 * w + quad * 4 + reg;
            int col = 16 * t + n;
            unsigned short h, l;
            bf16split(acc1[t][reg], h, l);
            sPH[eoff(row, col)] = h;
            sPL[eoff(row, col)] = l;
        }

    __syncthreads();   // the ONLY barrier: sFi/sFt now visible cross-wave

    // ---- M2: beta = fiC @ fi^T (A: sP own rows; B: sFi rows) ----
    short8 PAh[2], PAl[2];
    #pragma unroll
    for (int kk = 0; kk < 2; ++kk) {
        PAh[kk] = *(const short8*)&sPH[goff(arow, kk * 4 + quad)];
        PAl[kk] = *(const short8*)&sPL[goff(arow, kk * 4 + quad)];
    }
    floatx4 acc2[4];
    #pragma unroll
    for (int t = 0; t < 4; ++t) {
        floatx4 acc = {0.f, 0.f, 0.f, 0.f};
        const int brow = 16 * t + n;
        #pragma unroll
        for (int kk = 0; kk < 2; ++kk) {
            short8 bh = *(const short8*)&sFiH[goff(brow, kk * 4 + quad)];
            short8 bl = *(const short8*)&sFiL[goff(brow, kk * 4 + quad)];
            acc = __builtin_amdgcn_mfma_f32_16x16x32_bf16(PAh[kk], bh, acc, 0, 0, 0);
            acc = __builtin_amdgcn_mfma_f32_16x16x32_bf16(PAl[kk], bh, acc, 0, 0, 0);
            acc = __builtin_amdgcn_mfma_f32_16x16x32_bf16(PAh[kk], bl, acc, 0, 0, 0);
        }
        acc2[t] = acc;
    }

    // ---- masked row softmax, in-register ----
    float alv[4][4];
    #pragma unroll
    for (int reg = 0; reg < 4; ++reg) {
        const int row = 16 * w + quad * 4 + reg;
        float x[4];
        #pragma unroll
        for (int t = 0; t < 4; ++t) {
            x[t] = acc2[t][reg];
            if (row == 16 * t + n) x[t] = NEG_INF_V;
        }
        float m = fmaxf(fmaxf(x[0], x[1]), fmaxf(x[2], x[3]));
        m = rmax16(m);
        float s = 0.f;
        #pragma unroll
        for (int t = 0; t < 4; ++t) { x[t] = __expf(x[t] - m); s += x[t]; }
        s = rsum16(s);
        float inv = 1.0f / s;
        #pragma unroll
        for (int t = 0; t < 4; ++t) alv[reg][t] = x[t] * inv;
    }
    // alpha (hi only) overwrites sPH own rows — wave-private, no barrier
    #pragma unroll
    for (int reg = 0; reg < 4; ++reg)
        #pragma unroll
        for (int t = 0; t < 4; ++t) {
            int row = 16 * w + quad * 4 + reg;
            int col = 16 * t + n;
            sPH[eoff(row, col)] = bf16hi(alv[reg][t]);
        }

    // ---- M3: vi = alpha @ fi (single pass: alpha_h x fi_h) ----
    short8 AAh[2];
    #pragma unroll
    for (int kk = 0; kk < 2; ++kk)
        AAh[kk] = *(const short8*)&sPH[goff(arow, kk * 4 + quad)];
    floatx4 acc3[4];
    #pragma unroll
    for (int t = 0; t < 4; ++t) {
        floatx4 acc = {0.f, 0.f, 0.f, 0.f};
        const int brow = 16 * t + n;
        #pragma unroll
        for (int kk = 0; kk < 2; ++kk) {
            short8 bh = *(const short8*)&sFtH[goff(brow, kk * 4 + quad)];
            acc = __builtin_amdgcn_mfma_f32_16x16x32_bf16(AAh[kk], bh, acc, 0, 0, 0);
        }
        acc3[t] = acc;
    }

    // ---- LN + ReLU + final dot + sigmoid ----
    float gv[4], bv[4], w1v[4];
    #pragma unroll
    for (int t = 0; t < 4; ++t) {
        gv[t]  = ln_g[16 * t + n];
        bv[t]  = ln_b[16 * t + n];
        w1v[t] = lw[64 + 16 * t + n];
    }
    const float bias = lb[0];
    float res[4];
    #pragma unroll
    for (int reg = 0; reg < 4; ++reg) {
        const int row16 = quad * 4 + reg;
        float s = acc3[0][reg] + acc3[1][reg] + acc3[2][reg] + acc3[3][reg];
        s = rsum16(s);
        const float mu = s * (1.0f / 64.0f);
        float vs = 0.f;
        #pragma unroll
        for (int t = 0; t < 4; ++t) {
            float d = acc3[t][reg] - mu;
            vs += d * d;
        }
        vs = rsum16(vs) * (1.0f / 64.0f);
        const float rstd = rsqrtf(vs + LN_EPS);
        float dotp = 0.f;
        #pragma unroll
        for (int t = 0; t < 4; ++t) {
            float lnv = (acc3[t][reg] - mu) * rstd * gv[t] + bv[t];
            lnv = fmaxf(lnv, 0.f);
            dotp += lnv * w1v[t];
        }
        dotp = rsum16(dotp);
        const float d0row = __shfl(d0, row16 << 2, 64);  // fi[row].w0 from stager lane
        res[reg] = 1.0f / (1.0f + __expf(-(dotp + d0row + bias)));
    }
    if (n == 0) {
        float4 o = {res[0], res[1], res[2], res[3]};
        *(float4*)&out[blk * 64 + 16 * w + quad * 4] = o;
    }
}

extern "C" void kernel_launch(void* const* d_in, const int* in_sizes, int n_in,
                              void* d_out, int out_size, void* d_ws, size_t ws_size,
                              hipStream_t stream) {
    const float* fi   = (const float*)d_in[0];
    const float* corr = (const float*)d_in[1];
    const float* g    = (const float*)d_in[2];
    const float* b    = (const float*)d_in[3];
    const float* lw   = (const float*)d_in[4];
    const float* lb   = (const float*)d_in[5];
    float* out        = (float*)d_out;
    unsigned short* ct = (unsigned short*)d_ws;   // 16 KB: Ct_h | Ct_l

    const int B = in_sizes[0] / 4096;
    hipLaunchKernelGGL(prep_ct, dim3(16), dim3(256), 0, stream, corr, ct);
    hipLaunchKernelGGL(attn_mfma, dim3(B), dim3(256), 0, stream,
                       fi, ct, g, b, lw, lb, out);
}

// Round 7
// 238.187 us; speedup vs baseline: 1.6035x; 1.0513x over previous
//
#include <hip/hip_runtime.h>

typedef __attribute__((ext_vector_type(8))) short short8;
typedef __attribute__((ext_vector_type(4))) float floatx4;

constexpr float LN_EPS = 1e-5f;
constexpr float NEG_INF_V = -1e30f;

// software RNE fp32 -> bf16 (verified on HW in rounds 2-3)
__device__ __forceinline__ unsigned short bf16hi(float x) {
    unsigned int u = __builtin_bit_cast(unsigned int, x);
    u += 0x7FFFu + ((u >> 16) & 1u);
    return (unsigned short)(u >> 16);
}
__device__ __forceinline__ float bf16f(unsigned short h) {
    unsigned int u = ((unsigned int)h) << 16;
    return __builtin_bit_cast(float, u);
}
__device__ __forceinline__ void bf16split(float x, unsigned short& h, unsigned short& l) {
    h = bf16hi(x);
    l = bf16hi(x - bf16f(h));
}

// XOR-swizzled 64x64 bf16 LDS layout: 16B group g of row r at position g ^ (r & 7)
__device__ __forceinline__ int eoff(int r, int c) {
    return r * 64 + ((((c >> 3) ^ r) & 7) << 3) + (c & 7);
}
__device__ __forceinline__ int goff(int r, int g) {
    return r * 64 + (((g ^ r) & 7) << 3);
}

__device__ __forceinline__ float rsum16(float v) {
    v += __shfl_xor(v, 1, 64);
    v += __shfl_xor(v, 2, 64);
    v += __shfl_xor(v, 4, 64);
    v += __shfl_xor(v, 8, 64);
    return v;
}
__device__ __forceinline__ float rmax16(float v) {
    v = fmaxf(v, __shfl_xor(v, 1, 64));
    v = fmaxf(v, __shfl_xor(v, 2, 64));
    v = fmaxf(v, __shfl_xor(v, 4, 64));
    v = fmaxf(v, __shfl_xor(v, 8, 64));
    return v;
}

// C (64x64 fp32) -> C^T bf16 hi/lo in d_ws
__global__ void prep_ct(const float* __restrict__ corr,
                        unsigned short* __restrict__ ct) {
    int idx = blockIdx.x * 256 + threadIdx.x;
    int r = idx >> 6, c = idx & 63;
    float v = corr[idx];
    unsigned short h, l;
    bf16split(v, h, l);
    ct[c * 64 + r] = h;
    ct[4096 + c * 64 + r] = l;
}

__global__ __launch_bounds__(256, 4)
void attn_mfma(const float* __restrict__ fi,
               const unsigned short* __restrict__ Ct,
               const float* __restrict__ ln_g,
               const float* __restrict__ ln_b,
               const float* __restrict__ lw,
               const float* __restrict__ lb,
               float* __restrict__ out)
{
    // 5 x 8 KB = 40960 B -> 4 blocks/CU
    __shared__ __align__(16) unsigned short sFiH[4096], sFiL[4096]; // fi rows h/l
    __shared__ __align__(16) unsigned short sFtH[4096];             // fi^T rows, hi
    __shared__ __align__(16) unsigned short sPH[4096], sPL[4096];   // fiC h/l; sPH reused for alpha

    const int tid  = threadIdx.x;
    const int lane = tid & 63;
    const int w    = tid >> 6;
    const int n    = lane & 15;
    const int quad = lane >> 4;
    const size_t blk = blockIdx.x;

    // ---- staging: thread owns 16 elems of row r (wave-private rows) ----
    const int r = tid >> 2;
    const int a = tid & 3;
    float d0 = 0.f;
    {
        const float* fb = fi + blk * 4096 + (size_t)r * 64;
        #pragma unroll
        for (int i = 0; i < 4; ++i) {
            const int c = a * 4 + 16 * i;
            float4 v   = *(const float4*)(fb + c);
            float4 w0v = *(const float4*)&lw[c];
            d0 += v.x * w0v.x + v.y * w0v.y + v.z * w0v.z + v.w * w0v.w;
            unsigned short h0, l0, h1, l1, h2, l2, h3, l3;
            bf16split(v.x, h0, l0); bf16split(v.y, h1, l1);
            bf16split(v.z, h2, l2); bf16split(v.w, h3, l3);
            ushort4 H = {h0, h1, h2, h3};
            ushort4 L = {l0, l1, l2, l3};
            *(ushort4*)&sFiH[eoff(r, c)] = H;   // 8B-aligned (c%8 in {0,4})
            *(ushort4*)&sFiL[eoff(r, c)] = L;
            sFtH[eoff(c + 0, r)] = h0;
            sFtH[eoff(c + 1, r)] = h1;
            sFtH[eoff(c + 2, r)] = h2;
            sFtH[eoff(c + 3, r)] = h3;
        }
        d0 += __shfl_xor(d0, 1, 64);
        d0 += __shfl_xor(d0, 2, 64);   // 4 threads of row r all hold fi[r].w0
    }

    const int arow = 16 * w + n;

    // ---- M1: fiC = fi @ C (A: own-stripe sFi rows; B: C^T from global) ----
    short8 Ah[2], Al[2];
    #pragma unroll
    for (int kk = 0; kk < 2; ++kk) {
        Ah[kk] = *(const short8*)&sFiH[goff(arow, kk * 4 + quad)];
        Al[kk] = *(const short8*)&sFiL[goff(arow, kk * 4 + quad)];
    }
    floatx4 acc1[4];
    #pragma unroll
    for (int t = 0; t < 4; ++t) {
        floatx4 acc = {0.f, 0.f, 0.f, 0.f};
        const int brow = 16 * t + n;
        #pragma unroll
        for (int kk = 0; kk < 2; ++kk) {
            short8 bh = *(const short8*)&Ct[brow * 64 + kk * 32 + quad * 8];
            short8 bl = *(const short8*)&Ct[4096 + brow * 64 + kk * 32 + quad * 8];
            acc = __builtin_amdgcn_mfma_f32_16x16x32_bf16(Ah[kk], bh, acc, 0, 0, 0);
            acc = __builtin_amdgcn_mfma_f32_16x16x32_bf16(Al[kk], bh, acc, 0, 0, 0);
            acc = __builtin_amdgcn_mfma_f32_16x16x32_bf16(Ah[kk], bl, acc, 0, 0, 0);
        }
        acc1[t] = acc;
    }
    // fiC -> sP (wave-private rows)
    #pragma unroll
    for (int t = 0; t < 4; ++t) {
        const int col = 16 * t + n;
        const int row = 16 * w + quad * 4;
        #pragma unroll
        for (int reg = 0; reg < 4; ++reg) {
            unsigned short h, l;
            bf16split(acc1[t][reg], h, l);
            sPH[eoff(row + reg, col)] = h;
            sPL[eoff(row + reg, col)] = l;
        }
    }

    __syncthreads();   // the ONLY barrier

    // ---- M2: beta = fiC @ fi^T ----
    short8 PAh[2], PAl[2];
    #pragma unroll
    for (int kk = 0; kk < 2; ++kk) {
        PAh[kk] = *(const short8*)&sPH[goff(arow, kk * 4 + quad)];
        PAl[kk] = *(const short8*)&sPL[goff(arow, kk * 4 + quad)];
    }
    floatx4 acc2[4];
    #pragma unroll
    for (int t = 0; t < 4; ++t) {
        floatx4 acc = {0.f, 0.f, 0.f, 0.f};
        const int brow = 16 * t + n;
        #pragma unroll
        for (int kk = 0; kk < 2; ++kk) {
            short8 bh = *(const short8*)&sFiH[goff(brow, kk * 4 + quad)];
            short8 bl = *(const short8*)&sFiL[goff(brow, kk * 4 + quad)];
            acc = __builtin_amdgcn_mfma_f32_16x16x32_bf16(PAh[kk], bh, acc, 0, 0, 0);
            acc = __builtin_amdgcn_mfma_f32_16x16x32_bf16(PAl[kk], bh, acc, 0, 0, 0);
            acc = __builtin_amdgcn_mfma_f32_16x16x32_bf16(PAh[kk], bl, acc, 0, 0, 0);
        }
        acc2[t] = acc;
    }

    // ---- masked softmax, UNNORMALIZED (LN is scale-invariant; eps effect ~5e-5) ----
    #pragma unroll
    for (int reg = 0; reg < 4; ++reg) {
        const int row = 16 * w + quad * 4 + reg;
        float x[4];
        #pragma unroll
        for (int t = 0; t < 4; ++t) {
            x[t] = acc2[t][reg];
            if (row == 16 * t + n) x[t] = NEG_INF_V;
        }
        float m = fmaxf(fmaxf(x[0], x[1]), fmaxf(x[2], x[3]));
        m = rmax16(m);
        #pragma unroll
        for (int t = 0; t < 4; ++t) x[t] = __expf(x[t] - m);   // <= 1, no sum/divide
        sPH[eoff(row, 0 + n)]  = bf16hi(x[0]);   // alpha reuses sPH (own rows)
        sPH[eoff(row, 16 + n)] = bf16hi(x[1]);
        sPH[eoff(row, 32 + n)] = bf16hi(x[2]);
        sPH[eoff(row, 48 + n)] = bf16hi(x[3]);
    }

    // ---- M3: vi_unnorm = exp(beta-m) @ fi (hi-only single pass) ----
    short8 AAh[2];
    #pragma unroll
    for (int kk = 0; kk < 2; ++kk)
        AAh[kk] = *(const short8*)&sPH[goff(arow, kk * 4 + quad)];
    floatx4 acc3[4];
    #pragma unroll
    for (int t = 0; t < 4; ++t) {
        floatx4 acc = {0.f, 0.f, 0.f, 0.f};
        const int brow = 16 * t + n;
        #pragma unroll
        for (int kk = 0; kk < 2; ++kk) {
            short8 bh = *(const short8*)&sFtH[goff(brow, kk * 4 + quad)];
            acc = __builtin_amdgcn_mfma_f32_16x16x32_bf16(AAh[kk], bh, acc, 0, 0, 0);
        }
        acc3[t] = acc;
    }

    // ---- LN + ReLU + final dot + sigmoid ----
    float gv[4], bv[4], w1v[4];
    #pragma unroll
    for (int t = 0; t < 4; ++t) {
        gv[t]  = ln_g[16 * t + n];
        bv[t]  = ln_b[16 * t + n];
        w1v[t] = lw[64 + 16 * t + n];
    }
    const float bias = lb[0];
    float res[4];
    #pragma unroll
    for (int reg = 0; reg < 4; ++reg) {
        const int row16 = quad * 4 + reg;
        float s  = acc3[0][reg] + acc3[1][reg] + acc3[2][reg] + acc3[3][reg];
        float s2 = acc3[0][reg] * acc3[0][reg] + acc3[1][reg] * acc3[1][reg]
                 + acc3[2][reg] * acc3[2][reg] + acc3[3][reg] * acc3[3][reg];
        s  = rsum16(s);
        s2 = rsum16(s2);
        const float mu  = s * (1.0f / 64.0f);
        const float var = s2 * (1.0f / 64.0f) - mu * mu;
        const float rstd = __builtin_amdgcn_rsqf(var + LN_EPS);
        float dotp = 0.f;
        #pragma unroll
        for (int t = 0; t < 4; ++t) {
            float lnv = (acc3[t][reg] - mu) * rstd * gv[t] + bv[t];
            lnv = fmaxf(lnv, 0.f);
            dotp += lnv * w1v[t];
        }
        dotp = rsum16(dotp);
        const float d0row = __shfl(d0, row16 << 2, 64);
        res[reg] = __builtin_amdgcn_rcpf(1.0f + __expf(-(dotp + d0row + bias)));
    }
    if (n == 0) {
        float4 o = {res[0], res[1], res[2], res[3]};
        *(float4*)&out[blk * 64 + 16 * w + quad * 4] = o;
    }
}

extern "C" void kernel_launch(void* const* d_in, const int* in_sizes, int n_in,
                              void* d_out, int out_size, void* d_ws, size_t ws_size,
                              hipStream_t stream) {
    const float* fi   = (const float*)d_in[0];
    const float* corr = (const float*)d_in[1];
    const float* g    = (const float*)d_in[2];
    const float* b    = (const float*)d_in[3];
    const float* lw   = (const float*)d_in[4];
    const float* lb   = (const float*)d_in[5];
    float* out        = (float*)d_out;
    unsigned short* ct = (unsigned short*)d_ws;   // 16 KB: Ct_h | Ct_l

    const int B = in_sizes[0] / 4096;
    hipLaunchKernelGGL(prep_ct, dim3(16), dim3(256), 0, stream, corr, ct);
    hipLaunchKernelGGL(attn_mfma, dim3(B), dim3(256), 0, stream,
                       fi, ct, g, b, lw, lb, out);
}

// Round 8
// 225.454 us; speedup vs baseline: 1.6941x; 1.0565x over previous
//
#include <hip/hip_runtime.h>

typedef __attribute__((ext_vector_type(8))) short short8;
typedef __attribute__((ext_vector_type(4))) float floatx4;

constexpr float LN_EPS = 1e-5f;
constexpr float NEG_INF_V = -1e30f;

// software RNE fp32 -> bf16 (HW-verified rounds 2-3, 7)
__device__ __forceinline__ unsigned short bf16hi(float x) {
    unsigned int u = __builtin_bit_cast(unsigned int, x);
    u += 0x7FFFu + ((u >> 16) & 1u);
    return (unsigned short)(u >> 16);
}
__device__ __forceinline__ float bf16f(unsigned short h) {
    unsigned int u = ((unsigned int)h) << 16;
    return __builtin_bit_cast(float, u);
}
__device__ __forceinline__ void bf16split(float x, unsigned short& h, unsigned short& l) {
    h = bf16hi(x);
    l = bf16hi(x - bf16f(h));
}

// XOR-swizzled 64x64 bf16 LDS layout: 16B group g of row r at position g ^ (r & 7)
__device__ __forceinline__ int eoff(int r, int c) {
    return r * 64 + ((((c >> 3) ^ r) & 7) << 3) + (c & 7);
}
__device__ __forceinline__ int goff(int r, int g) {
    return r * 64 + (((g ^ r) & 7) << 3);
}

__device__ __forceinline__ float rsum16(float v) {
    v += __shfl_xor(v, 1, 64);
    v += __shfl_xor(v, 2, 64);
    v += __shfl_xor(v, 4, 64);
    v += __shfl_xor(v, 8, 64);
    return v;
}
__device__ __forceinline__ float rmax16(float v) {
    v = fmaxf(v, __shfl_xor(v, 1, 64));
    v = fmaxf(v, __shfl_xor(v, 2, 64));
    v = fmaxf(v, __shfl_xor(v, 4, 64));
    v = fmaxf(v, __shfl_xor(v, 8, 64));
    return v;
}

__global__ __launch_bounds__(256, 4)
void attn_mfma(const float* __restrict__ fi,
               const float* __restrict__ corr,
               const float* __restrict__ ln_g,
               const float* __restrict__ ln_b,
               const float* __restrict__ lw,
               const float* __restrict__ lb,
               float* __restrict__ out)
{
    // 5 x 8 KB = 40960 B -> 4 blocks/CU
    __shared__ __align__(16) unsigned short sFiH[4096], sFiL[4096]; // fi rows h/l
    __shared__ __align__(16) unsigned short sFtH[4096];             // fi^T rows, hi
    // sPH/sPL: phase 1 = C^T h/l (staged per block); phase 2 = fiC h/l; sPH phase 3 = alpha
    __shared__ __align__(16) unsigned short sPH[4096], sPL[4096];

    const int tid  = threadIdx.x;
    const int lane = tid & 63;
    const int w    = tid >> 6;
    const int n    = lane & 15;
    const int quad = lane >> 4;
    const size_t blk = blockIdx.x;

    // ---- staging: thread owns 16 elems of fi row r (wave-private stripe) ----
    const int r = tid >> 2;
    const int a = tid & 3;
    float d0 = 0.f;
    {
        const float* fb = fi + blk * 4096 + (size_t)r * 64;
        #pragma unroll
        for (int i = 0; i < 4; ++i) {
            const int c = a * 4 + 16 * i;
            float4 v   = *(const float4*)(fb + c);
            float4 w0v = *(const float4*)&lw[c];
            d0 += v.x * w0v.x + v.y * w0v.y + v.z * w0v.z + v.w * w0v.w;
            unsigned short h0, l0, h1, l1, h2, l2, h3, l3;
            bf16split(v.x, h0, l0); bf16split(v.y, h1, l1);
            bf16split(v.z, h2, l2); bf16split(v.w, h3, l3);
            ushort4 H = {h0, h1, h2, h3};
            ushort4 L = {l0, l1, l2, l3};
            *(ushort4*)&sFiH[eoff(r, c)] = H;   // 8B-aligned (c%8 in {0,4})
            *(ushort4*)&sFiL[eoff(r, c)] = L;
            sFtH[eoff(c + 0, r)] = h0;
            sFtH[eoff(c + 1, r)] = h1;
            sFtH[eoff(c + 2, r)] = h2;
            sFtH[eoff(c + 3, r)] = h3;
        }
        d0 += __shfl_xor(d0, 1, 64);
        d0 += __shfl_xor(d0, 2, 64);   // 4 threads of row r all hold fi[r].w0
    }
    // ---- stage C^T h/l into dead sPH/sPL (corr is L1-hot after first block) ----
    {
        const float* cb = corr + (size_t)r * 64;
        #pragma unroll
        for (int i = 0; i < 4; ++i) {
            const int c = a * 4 + 16 * i;
            float4 v = *(const float4*)(cb + c);
            unsigned short h0, l0, h1, l1, h2, l2, h3, l3;
            bf16split(v.x, h0, l0); bf16split(v.y, h1, l1);
            bf16split(v.z, h2, l2); bf16split(v.w, h3, l3);
            sPH[eoff(c + 0, r)] = h0;  sPL[eoff(c + 0, r)] = l0;  // Ct[col][row]
            sPH[eoff(c + 1, r)] = h1;  sPL[eoff(c + 1, r)] = l1;
            sPH[eoff(c + 2, r)] = h2;  sPL[eoff(c + 2, r)] = l2;
            sPH[eoff(c + 3, r)] = h3;  sPL[eoff(c + 3, r)] = l3;
        }
    }
    __syncthreads();   // bar1: sFi/sFt/Ct visible

    const int arow = 16 * w + n;

    // ---- M1: fiC = fi @ C (A: own-stripe sFi rows h/l; B: Ct h/l from LDS) ----
    short8 Ah[2], Al[2];
    #pragma unroll
    for (int kk = 0; kk < 2; ++kk) {
        Ah[kk] = *(const short8*)&sFiH[goff(arow, kk * 4 + quad)];
        Al[kk] = *(const short8*)&sFiL[goff(arow, kk * 4 + quad)];
    }
    floatx4 acc1[4];
    #pragma unroll
    for (int t = 0; t < 4; ++t) {
        floatx4 acc = {0.f, 0.f, 0.f, 0.f};
        const int brow = 16 * t + n;
        #pragma unroll
        for (int kk = 0; kk < 2; ++kk) {
            short8 bh = *(const short8*)&sPH[goff(brow, kk * 4 + quad)];
            short8 bl = *(const short8*)&sPL[goff(brow, kk * 4 + quad)];
            acc = __builtin_amdgcn_mfma_f32_16x16x32_bf16(Ah[kk], bh, acc, 0, 0, 0);
            acc = __builtin_amdgcn_mfma_f32_16x16x32_bf16(Al[kk], bh, acc, 0, 0, 0);
            acc = __builtin_amdgcn_mfma_f32_16x16x32_bf16(Ah[kk], bl, acc, 0, 0, 0);
        }
        acc1[t] = acc;
    }

    __syncthreads();   // bar2: all waves done reading Ct from sPH/sPL

    // fiC -> sP (wave-private rows overwrite Ct)
    #pragma unroll
    for (int t = 0; t < 4; ++t) {
        const int col = 16 * t + n;
        const int row = 16 * w + quad * 4;
        #pragma unroll
        for (int reg = 0; reg < 4; ++reg) {
            unsigned short h, l;
            bf16split(acc1[t][reg], h, l);
            sPH[eoff(row + reg, col)] = h;
            sPL[eoff(row + reg, col)] = l;
        }
    }

    // ---- M2: beta = fiC @ fi^T (A: own sP rows, self-written; B: sFi rows) ----
    short8 PAh[2], PAl[2];
    #pragma unroll
    for (int kk = 0; kk < 2; ++kk) {
        PAh[kk] = *(const short8*)&sPH[goff(arow, kk * 4 + quad)];
        PAl[kk] = *(const short8*)&sPL[goff(arow, kk * 4 + quad)];
    }
    floatx4 acc2[4];
    #pragma unroll
    for (int t = 0; t < 4; ++t) {
        floatx4 acc = {0.f, 0.f, 0.f, 0.f};
        const int brow = 16 * t + n;
        #pragma unroll
        for (int kk = 0; kk < 2; ++kk) {
            short8 bh = *(const short8*)&sFiH[goff(brow, kk * 4 + quad)];
            short8 bl = *(const short8*)&sFiL[goff(brow, kk * 4 + quad)];
            acc = __builtin_amdgcn_mfma_f32_16x16x32_bf16(PAh[kk], bh, acc, 0, 0, 0);
            acc = __builtin_amdgcn_mfma_f32_16x16x32_bf16(PAl[kk], bh, acc, 0, 0, 0);
            acc = __builtin_amdgcn_mfma_f32_16x16x32_bf16(PAh[kk], bl, acc, 0, 0, 0);
        }
        acc2[t] = acc;
    }

    // ---- masked softmax, UNNORMALIZED (LN is scale-invariant; eps effect ~5e-5) ----
    #pragma unroll
    for (int reg = 0; reg < 4; ++reg) {
        const int row = 16 * w + quad * 4 + reg;
        float x[4];
        #pragma unroll
        for (int t = 0; t < 4; ++t) {
            x[t] = acc2[t][reg];
            if (row == 16 * t + n) x[t] = NEG_INF_V;
        }
        float m = fmaxf(fmaxf(x[0], x[1]), fmaxf(x[2], x[3]));
        m = rmax16(m);
        #pragma unroll
        for (int t = 0; t < 4; ++t) x[t] = __expf(x[t] - m);   // <= 1, no sum/divide
        sPH[eoff(row, 0 + n)]  = bf16hi(x[0]);   // alpha reuses sPH (own rows)
        sPH[eoff(row, 16 + n)] = bf16hi(x[1]);
        sPH[eoff(row, 32 + n)] = bf16hi(x[2]);
        sPH[eoff(row, 48 + n)] = bf16hi(x[3]);
    }

    // ---- M3: vi_unnorm = exp(beta-m) @ fi (hi-only single pass) ----
    short8 AAh[2];
    #pragma unroll
    for (int kk = 0; kk < 2; ++kk)
        AAh[kk] = *(const short8*)&sPH[goff(arow, kk * 4 + quad)];
    floatx4 acc3[4];
    #pragma unroll
    for (int t = 0; t < 4; ++t) {
        floatx4 acc = {0.f, 0.f, 0.f, 0.f};
        const int brow = 16 * t + n;
        #pragma unroll
        for (int kk = 0; kk < 2; ++kk) {
            short8 bh = *(const short8*)&sFtH[goff(brow, kk * 4 + quad)];
            acc = __builtin_amdgcn_mfma_f32_16x16x32_bf16(AAh[kk], bh, acc, 0, 0, 0);
        }
        acc3[t] = acc;
    }

    // ---- LN + ReLU + final dot + sigmoid ----
    float gv[4], bv[4], w1v[4];
    #pragma unroll
    for (int t = 0; t < 4; ++t) {
        gv[t]  = ln_g[16 * t + n];
        bv[t]  = ln_b[16 * t + n];
        w1v[t] = lw[64 + 16 * t + n];
    }
    const float bias = lb[0];
    float res[4];
    #pragma unroll
    for (int reg = 0; reg < 4; ++reg) {
        const int row16 = quad * 4 + reg;
        float s  = acc3[0][reg] + acc3[1][reg] + acc3[2][reg] + acc3[3][reg];
        float s2 = acc3[0][reg] * acc3[0][reg] + acc3[1][reg] * acc3[1][reg]
                 + acc3[2][reg] * acc3[2][reg] + acc3[3][reg] * acc3[3][reg];
        s  = rsum16(s);
        s2 = rsum16(s2);
        const float mu  = s * (1.0f / 64.0f);
        const float var = s2 * (1.0f / 64.0f) - mu * mu;
        const float rstd = __builtin_amdgcn_rsqf(var + LN_EPS);
        float dotp = 0.f;
        #pragma unroll
        for (int t = 0; t < 4; ++t) {
            float lnv = (acc3[t][reg] - mu) * rstd * gv[t] + bv[t];
            lnv = fmaxf(lnv, 0.f);
            dotp += lnv * w1v[t];
        }
        dotp = rsum16(dotp);
        const float d0row = __shfl(d0, row16 << 2, 64);
        res[reg] = __builtin_amdgcn_rcpf(1.0f + __expf(-(dotp + d0row + bias)));
    }
    if (n == 0) {
        float4 o = {res[0], res[1], res[2], res[3]};
        *(float4*)&out[blk * 64 + 16 * w + quad * 4] = o;
    }
}

extern "C" void kernel_launch(void* const* d_in, const int* in_sizes, int n_in,
                              void* d_out, int out_size, void* d_ws, size_t ws_size,
                              hipStream_t stream) {
    const float* fi   = (const float*)d_in[0];
    const float* corr = (const float*)d_in[1];
    const float* g    = (const float*)d_in[2];
    const float* b    = (const float*)d_in[3];
    const float* lw   = (const float*)d_in[4];
    const float* lb   = (const float*)d_in[5];
    float* out        = (float*)d_out;

    const int B = in_sizes[0] / 4096;
    hipLaunchKernelGGL(attn_mfma, dim3(B), dim3(256), 0, stream,
                       fi, corr, g, b, lw, lb, out);
}